// Round 11
// baseline (1399.158 us; speedup 1.0000x reference)
//
#include <hip/hip_runtime.h>
#include <cstdint>
#include <cstddef>

#define SEQ 128
#define BATCH 64
#define NVOCAB 10000
#define NREC 64
#define NWORK 192
#define NTOT 256

typedef __attribute__((ext_vector_type(8))) short short8;
typedef __attribute__((ext_vector_type(4))) float f32x4;

__device__ __forceinline__ unsigned short f2b(float f) {
  union { float f; unsigned u; } c; c.f = f;
  unsigned u = c.u;
  unsigned r = (u + 0x7fffu + ((u >> 16) & 1u)) >> 16;
  return (unsigned short)r;
}

__device__ __forceinline__ f32x4 mfma16(short8 a, short8 b, f32x4 c) {
  return __builtin_amdgcn_mfma_f32_16x16x32_bf16(a, b, c, 0, 0, 0);
}

// Coherent (cross-XCD) ops: bypass L1+L2, served at the coherence point.
__device__ __forceinline__ short8 ldg_coh(const unsigned short* p) {
  short8 r;
  asm volatile("global_load_dwordx4 %0, %1, off sc0 sc1" : "=v"(r) : "v"(p));
  return r;
}
__device__ __forceinline__ void stg_coh2(unsigned short* p, int v) {
  asm volatile("global_store_short %0, %1, off sc0 sc1" :: "v"(p), "v"(v) : "memory");
}
__device__ __forceinline__ void st_stamp(int* p, int v) {
  asm volatile("global_store_dword %0, %1, off sc0 sc1" :: "v"(p), "v"(v) : "memory");
}
__device__ __forceinline__ int ld_stamp(const int* p) {
  int r;
  asm volatile("global_load_dword %0, %1, off sc0 sc1" : "=v"(r) : "v"(p));
  return r;
}

// Per-wave wait: all 32 words of one stamp line >= need.
template<int SLP>
__device__ __forceinline__ void wait_line(const int* line, int need, int guard_max) {
  if (need < 0) return;
  int idx = threadIdx.x & 31;
  int guard = 0;
  for (;;) {
    int v = ld_stamp(line + idx);
    asm volatile("s_waitcnt vmcnt(0)" ::: "memory");
    if (__all(v >= need)) return;
    __builtin_amdgcn_s_sleep(SLP);
    if (++guard > guard_max) return;  // bail to wrong-output, never hang
  }
}

// ---------------- packing: src f32 (K x N row-major) -> frag-linear bf16 ----
__global__ void pack_frag(const float* __restrict__ src, unsigned short* __restrict__ dst,
                          int ksteps, int row_off, int src_ld, int ntiles, int mode, int nreal) {
  int tid = blockIdx.x * 256 + threadIdx.x;
  int total = ntiles * ksteps * 64;
  if (tid >= total) return;
  int l = tid & 63;
  int ks = (tid >> 6) % ksteps;
  int nt = tid / (64 * ksteps);
  int n = nt * 16 + (l & 15);
  int col;
  bool valid = true;
  if (mode == 1) {
    int jc = n >> 5, s = n & 31;
    col = (s < 16) ? (16 * jc + s) : (512 + 16 * jc + (s - 16));
  } else {
    col = n;
    valid = (n < nreal);
  }
  int k0 = row_off + ks * 32 + ((l >> 4) << 3);
  short8 o;
  for (int j = 0; j < 8; ++j) {
    float x = valid ? src[(size_t)(k0 + j) * src_ld + col] : 0.f;
    o[j] = (short)f2b(x);
  }
  *reinterpret_cast<short8*>(&dst[(size_t)tid * 8]) = o;
}

__global__ void pack_bias(const float* __restrict__ bg0, const float* __restrict__ bg1,
                          float* __restrict__ bg0p, float* __restrict__ bg1p) {
  int p = blockIdx.x * 256 + threadIdx.x;
  if (p >= 1024) return;
  int jc = p >> 5, s = p & 31;
  int col = (s < 16) ? (16 * jc + s) : (512 + 16 * jc + (s - 16));
  bg0p[p] = bg0[col];
  bg1p[p] = bg1[col];
}

// ------------- embedding gather into kmat layout [t][ktile][row][8] bf16 ----
__global__ void embed_gather(const int* __restrict__ inp, const float* __restrict__ tab,
                             unsigned short* __restrict__ XA) {
  int tid = blockIdx.x * 256 + threadIdx.x;
  if (tid >= SEQ * 64 * 64) return;
  int row = tid & 63;
  int kt = (tid >> 6) & 63;
  int t = tid >> 12;
  int v = inp[t * BATCH + row];
  const float* s = &tab[(size_t)v * 512 + kt * 8];
  const float scale = 22.627416997969522f; // sqrt(512)
  short8 o;
  for (int j = 0; j < 8; ++j) o[j] = (short)f2b(s[j] * scale);
  *reinterpret_cast<short8*>(&XA[(size_t)tid * 8]) = o;
}

// ------------- init: h0/h1 init (ROW-MAJOR bf16 [64][512]), stamps=-1 ----
__global__ void init_states(const float* __restrict__ hid, unsigned short* __restrict__ H0INITB,
                            unsigned short* __restrict__ H1INITB, int* __restrict__ stamps) {
  int idx = blockIdx.x * 256 + threadIdx.x;
  if (idx < 3072) stamps[idx] = -1;
  if (idx >= 64 * 512) return;
  H0INITB[idx] = f2b(hid[idx]);
  H1INITB[idx] = f2b(hid[64 * 512 + idx]);
}

// ------------- generic 128x128 LDS-tiled bf16 GEMM, K=512 (prologue only) ----
__launch_bounds__(256, 2)
__global__ void gemm128(const unsigned short* __restrict__ A, const unsigned short* __restrict__ Bf,
                        const float* __restrict__ bias, float* __restrict__ C,
                        int Nld, int Nreal) {
  __shared__ __align__(16) unsigned short ldsA[16 * 512];
  __shared__ __align__(16) unsigned short ldsB[16 * 512];
  int nb = blockIdx.x, yb = blockIdx.y;
  int l = threadIdx.x & 63, w = threadIdx.x >> 6;
  int mh = w >> 1, nh = w & 1;
  f32x4 acc[4][4] = {};
  for (int ko = 0; ko < 8; ++ko) {
    __syncthreads();
    for (int j = 0; j < 4; ++j) {
      int c = w * 4 + j;
      int m8 = c >> 1, ks = c & 1;
      int t = yb * 2 + (m8 >> 2);
      int kt = ko * 8 + ks * 4 + (l >> 4);
      int row = (m8 & 3) * 16 + (l & 15);
      size_t gidx = (((size_t)t * 64 + kt) * 64 + row) * 8;
      *reinterpret_cast<short8*>(&ldsA[(size_t)c * 512 + l * 8]) =
          *reinterpret_cast<const short8*>(&A[gidx]);
      size_t gb = (((size_t)(nb * 8 + (c >> 1)) * 16) + (size_t)(ko * 2 + (c & 1))) * 512 + (size_t)l * 8;
      *reinterpret_cast<short8*>(&ldsB[(size_t)c * 512 + l * 8]) =
          *reinterpret_cast<const short8*>(&Bf[gb]);
    }
    __syncthreads();
    for (int ks = 0; ks < 2; ++ks) {
      short8 a[4], b[4];
      for (int mt = 0; mt < 4; ++mt) {
        int m8 = mh * 4 + mt;
        a[mt] = *reinterpret_cast<const short8*>(&ldsA[((size_t)(m8 * 2 + ks) * 64 + l) * 8]);
      }
      for (int nt = 0; nt < 4; ++nt) {
        int n8 = nh * 4 + nt;
        b[nt] = *reinterpret_cast<const short8*>(&ldsB[((size_t)(n8 * 2 + ks) * 64 + l) * 8]);
      }
      for (int mt = 0; mt < 4; ++mt)
        for (int nt = 0; nt < 4; ++nt)
          acc[mt][nt] = mfma16(a[mt], b[nt], acc[mt][nt]);
    }
  }
  for (int mt = 0; mt < 4; ++mt) {
    for (int nt = 0; nt < 4; ++nt) {
      int col = nb * 128 + nh * 64 + nt * 16 + (l & 15);
      if (col >= Nreal) continue;
      float bv = bias[col];
      int row0 = yb * 128 + mh * 64 + mt * 16 + ((l >> 4) << 2);
      for (int r = 0; r < 4; ++r)
        C[(size_t)(row0 + r) * Nld + col] = acc[mt][nt][r] + bv;
    }
  }
}

// ------------- recurrence: per-wave pipelines, M-split, LDS weights ----
// Exchange buffers are ROW-MAJOR bf16 [64][512]. Wave w of WG g owns output
// block rows [16w,16w+16) x cols [16g,16g+16). No __syncthreads in the loop;
// each wave waits/stamps independently. Stamp lines (32 words, 2 reps):
// L = w (SR0), 4+w (SR1), 8+w (SH0), 12+w (SH1); ptr = stamps+(L*2+rep)*64.
// SHW (workers): stamps+2048+(w*4+rep)*64, 4 reps.
template<int KS, int LAYER>
__device__ void rec_layer(
    int g, const unsigned short* __restrict__ Wg, const unsigned short* __restrict__ Wc,
    const float* __restrict__ Xg0p, const float* __restrict__ Xc0p,
    const float* __restrict__ bg1p, const float* __restrict__ bc1,
    const float* __restrict__ hidden,
    unsigned short* __restrict__ H0ALL, unsigned short* __restrict__ H1ALL,
    const unsigned short* __restrict__ H0INITB, const unsigned short* __restrict__ H1INITB,
    unsigned short* __restrict__ RH0, unsigned short* __restrict__ RH1,
    int* __restrict__ stamps, float* __restrict__ hidden_out, char* smem) {
  const int tid = threadIdx.x;
  const int l = tid & 63, w = tid >> 6;
  const int s = l & 15, q = l >> 4;

  // ---- weights -> LDS (once) ----
  unsigned short* WgL = (unsigned short*)smem;   // [2*KS][64][8]
  unsigned short* WcL = WgL + 2 * KS * 512;      // [KS][64][8]
  {
    const short8* srcG = reinterpret_cast<const short8*>(Wg + (size_t)(2 * g) * KS * 512);
    short8* dstG = reinterpret_cast<short8*>(WgL);
    for (int i = tid; i < 2 * KS * 64; i += 256) dstG[i] = srcG[i];
    const short8* srcC = reinterpret_cast<const short8*>(Wc + (size_t)g * KS * 512);
    short8* dstC = reinterpret_cast<short8*>(WcL);
    for (int i = tid; i < KS * 64; i += 256) dstC[i] = srcC[i];
  }
  __syncthreads();

  const int myrow0 = 16 * w + q * 4;
  const int mycol = 16 * g + s;
  const int arow = (16 * w + s) * 512 + q * 8;   // A-frag base (row-major)

  // f32 h master in registers
  float hf[4];
#pragma unroll
  for (int j = 0; j < 4; ++j)
    hf[j] = hidden[(size_t)LAYER * 32768 + (size_t)(myrow0 + j) * 512 + mycol];

  const int rep = g & 1;
  int* SRl  = stamps + (((LAYER ? 4 : 0) + w) * 2 + rep) * 64;
  int* SH0l = stamps + ((8 + w) * 2 + rep) * 64;
  int* SH1l = stamps + ((12 + w) * 2 + rep) * 64;
  int* SRw  = stamps + (((LAYER ? 4 : 0) + w) * 2) * 64;   // write base (rep0; rep1=+64)
  int* SHw  = stamps + (((LAYER ? 12 : 8) + w) * 2) * 64;
  int* SHWw = stamps + 2048 + (w * 4) * 64;
  unsigned short* myRH = LAYER ? RH1 : RH0;

  float bgu = 0.f, bgr = 0.f, bcv = 0.f;
  if (LAYER) { bgu = bg1p[g * 32 + s]; bgr = bg1p[g * 32 + 16 + s]; bcv = bc1[16 * g + s]; }

  short8 aH0[LAYER ? 16 : 1];  // L1: h0 frags stashed A->B

  for (int t = 0; t < 128; ++t) {
    // ---- L0: X-part prefetch (no dependency) ----
    float xu[4], xr[4], xc[4];
    if constexpr (LAYER == 0) {
#pragma unroll
      for (int j = 0; j < 4; ++j) {
        size_t rb = (size_t)(t * 64 + myrow0 + j);
        xu[j] = Xg0p[rb * 1024 + g * 32 + s];
        xr[j] = Xg0p[rb * 1024 + g * 32 + 16 + s];
        xc[j] = Xc0p[rb * 512 + 16 * g + s];
      }
    }
    const unsigned short* A0;
    const unsigned short* A1 = nullptr;
    if constexpr (LAYER) {
      A0 = H0ALL + (size_t)t * 32768;
      A1 = t ? (H1ALL + (size_t)(t - 1) * 32768) : H1INITB;
    } else {
      A0 = t ? (H0ALL + (size_t)(t - 1) * 32768) : H0INITB;
    }

    // ============ phase A: gates ============
    f32x4 accU = {}, accR = {};
    if constexpr (LAYER == 0) {
      wait_line<1>(SH0l, t - 1, 3000000);
      short8 a[16];
#pragma unroll
      for (int ks = 0; ks < 16; ++ks) a[ks] = ldg_coh(&A0[(size_t)arow + ks * 32]);
      asm volatile("s_waitcnt vmcnt(0)" ::: "memory");
      __builtin_amdgcn_sched_barrier(0);
#pragma unroll
      for (int ks = 0; ks < 16; ++ks) {
        short8 bU = *reinterpret_cast<const short8*>(&WgL[(size_t)(0 * KS + ks) * 512 + l * 8]);
        short8 bR = *reinterpret_cast<const short8*>(&WgL[(size_t)(1 * KS + ks) * 512 + l * 8]);
        accU = mfma16(a[ks], bU, accU);
        accR = mfma16(a[ks], bR, accR);
      }
    } else {
      wait_line<1>(SH0l, t, 3000000);
      wait_line<1>(SH1l, t - 1, 3000000);
#pragma unroll
      for (int ks = 0; ks < 16; ++ks) aH0[ks] = ldg_coh(&A0[(size_t)arow + ks * 32]);
      asm volatile("s_waitcnt vmcnt(0)" ::: "memory");
      __builtin_amdgcn_sched_barrier(0);
      short8 aH1[16];
#pragma unroll
      for (int ks = 0; ks < 16; ++ks) aH1[ks] = ldg_coh(&A1[(size_t)arow + ks * 32]);
      // overlap: h0 MFMAs while h1 loads fly
#pragma unroll
      for (int ks = 0; ks < 16; ++ks) {
        short8 bU = *reinterpret_cast<const short8*>(&WgL[(size_t)(0 * KS + ks) * 512 + l * 8]);
        short8 bR = *reinterpret_cast<const short8*>(&WgL[(size_t)(1 * KS + ks) * 512 + l * 8]);
        accU = mfma16(aH0[ks], bU, accU);
        accR = mfma16(aH0[ks], bR, accR);
      }
      asm volatile("s_waitcnt vmcnt(0)" ::: "memory");
      __builtin_amdgcn_sched_barrier(0);
#pragma unroll
      for (int ks = 0; ks < 16; ++ks) {
        short8 bU = *reinterpret_cast<const short8*>(&WgL[(size_t)(0 * KS + 16 + ks) * 512 + l * 8]);
        short8 bR = *reinterpret_cast<const short8*>(&WgL[(size_t)(1 * KS + 16 + ks) * 512 + l * 8]);
        accU = mfma16(aH1[ks], bU, accU);
        accR = mfma16(aH1[ks], bR, accR);
      }
    }
    // epilogue A: u stays in regs; rh -> 2B coherent stores (coalesce to 32B)
    float u_[4];
#pragma unroll
    for (int j = 0; j < 4; ++j) {
      float su = accU[j] + (LAYER ? bgu : xu[j]);
      float sr = accR[j] + (LAYER ? bgr : xr[j]);
      u_[j] = 1.f / (1.f + __expf(-su));
      float rh = (1.f / (1.f + __expf(-sr))) * hf[j];
      stg_coh2(&myRH[(size_t)(myrow0 + j) * 512 + mycol], (int)f2b(rh));
    }
    asm volatile("s_waitcnt vmcnt(0)" ::: "memory");
    if (l == 0) { st_stamp(&SRw[g], t); st_stamp(&SRw[64 + g], t); }

    // ============ phase B: cell + state update ============
    f32x4 acc = {};
    if constexpr (LAYER == 0) {
      wait_line<1>(SRl, t, 3000000);
      short8 a[16];
#pragma unroll
      for (int ks = 0; ks < 16; ++ks) a[ks] = ldg_coh(&RH0[(size_t)arow + ks * 32]);
      asm volatile("s_waitcnt vmcnt(0)" ::: "memory");
      __builtin_amdgcn_sched_barrier(0);
#pragma unroll
      for (int ks = 0; ks < 16; ++ks) {
        short8 bC = *reinterpret_cast<const short8*>(&WcL[(size_t)ks * 512 + l * 8]);
        acc = mfma16(a[ks], bC, acc);
      }
    } else {
      wait_line<1>(SRl, t, 3000000);
      short8 a[16];
#pragma unroll
      for (int ks = 0; ks < 16; ++ks) a[ks] = ldg_coh(&RH1[(size_t)arow + ks * 32]);
      // overlap: stashed-h0 MFMAs while rh1 loads fly
#pragma unroll
      for (int ks = 0; ks < 16; ++ks) {
        short8 bC = *reinterpret_cast<const short8*>(&WcL[(size_t)ks * 512 + l * 8]);
        acc = mfma16(aH0[ks], bC, acc);
      }
      asm volatile("s_waitcnt vmcnt(0)" ::: "memory");
      __builtin_amdgcn_sched_barrier(0);
#pragma unroll
      for (int ks = 0; ks < 16; ++ks) {
        short8 bC = *reinterpret_cast<const short8*>(&WcL[(size_t)(16 + ks) * 512 + l * 8]);
        acc = mfma16(a[ks], bC, acc);
      }
    }
    // epilogue B
    unsigned short* Hdst = (LAYER ? H1ALL : H0ALL) + (size_t)t * 32768;
#pragma unroll
    for (int j = 0; j < 4; ++j) {
      float sc = acc[j] + (LAYER ? bcv : xc[j]);
      float cv = tanhf(sc);
      float hn = hf[j] + u_[j] * (cv - hf[j]);
      hf[j] = hn;
      stg_coh2(&Hdst[(size_t)(myrow0 + j) * 512 + mycol], (int)f2b(hn));
    }
    asm volatile("s_waitcnt vmcnt(0)" ::: "memory");
    if (l == 0) {
      st_stamp(&SHw[g], t); st_stamp(&SHw[64 + g], t);
      if constexpr (LAYER) {
#pragma unroll
        for (int r4 = 0; r4 < 4; ++r4) st_stamp(&SHWw[r4 * 64 + g], t);
      }
    }
  }

  // ---- final hidden (f32) from registers ----
#pragma unroll
  for (int j = 0; j < 4; ++j)
    hidden_out[(size_t)LAYER * 32768 + (size_t)(myrow0 + j) * 512 + mycol] = hf[j];
}

// ------------- worker path: logits tiles (A is row-major H1ALL ring) ----
__device__ void worker_path(int wid, const unsigned short* __restrict__ A,
                            const unsigned short* __restrict__ Bf,
                            const float* __restrict__ bias, float* __restrict__ C,
                            const int* __restrict__ stamps, char* smem) {
  unsigned short* ldsA = (unsigned short*)smem;
  unsigned short* ldsB = (unsigned short*)(smem + 16384);
  int l = threadIdx.x & 63, w = threadIdx.x >> 6;
  int mh = w >> 1, nh = w & 1;
  int nb = wid % 80;
  int helper = wid / 80;
  int nhelp = (nb < 32) ? 3 : 2;
  const int rep4 = wid & 3;
  for (int tp = helper; tp < 64; tp += nhelp) {
    if (w == 0) {  // single-wave poll: all 4 SHW row-block lines >= 2tp+1
      for (int w4 = 0; w4 < 4; ++w4)
        wait_line<32>(stamps + 2048 + (w4 * 4 + rep4) * 64, 2 * tp + 1, 50000);
    }
    __syncthreads();
    f32x4 acc[4][4] = {};
    for (int ko = 0; ko < 8; ++ko) {
      __syncthreads();
      for (int j = 0; j < 4; ++j) {
        int c = w * 4 + j;
        int m8 = c >> 1, ks = c & 1;
        int t = tp * 2 + (m8 >> 2);
        int kt = ko * 8 + ks * 4 + (l >> 4);
        int row = (m8 & 3) * 16 + (l & 15);
        size_t gidx = ((size_t)(t * 64 + row)) * 512 + (size_t)kt * 8;  // row-major A
        *reinterpret_cast<short8*>(&ldsA[(size_t)c * 512 + l * 8]) =
            *reinterpret_cast<const short8*>(&A[gidx]);
        size_t gb = (((size_t)(nb * 8 + (c >> 1)) * 16) + (size_t)(ko * 2 + (c & 1))) * 512 + (size_t)l * 8;
        *reinterpret_cast<short8*>(&ldsB[(size_t)c * 512 + l * 8]) =
            *reinterpret_cast<const short8*>(&Bf[gb]);
      }
      __syncthreads();
      for (int ks = 0; ks < 2; ++ks) {
        short8 a[4], b[4];
        for (int mt = 0; mt < 4; ++mt)
          a[mt] = *reinterpret_cast<const short8*>(&ldsA[((size_t)((mh * 4 + mt) * 2 + ks) * 64 + l) * 8]);
        for (int nt = 0; nt < 4; ++nt)
          b[nt] = *reinterpret_cast<const short8*>(&ldsB[((size_t)((nh * 4 + nt) * 2 + ks) * 64 + l) * 8]);
        for (int mt = 0; mt < 4; ++mt)
          for (int nt = 0; nt < 4; ++nt)
            acc[mt][nt] = mfma16(a[mt], b[nt], acc[mt][nt]);
      }
    }
    for (int mt = 0; mt < 4; ++mt) {
      for (int nt = 0; nt < 4; ++nt) {
        int col = nb * 128 + nh * 64 + nt * 16 + (l & 15);
        if (col >= NVOCAB) continue;
        float bv = bias[col];
        int row0 = tp * 128 + mh * 64 + mt * 16 + ((l >> 4) << 2);
        for (int r = 0; r < 4; ++r)
          C[(size_t)(row0 + r) * NVOCAB + col] = acc[mt][nt][r] + bv;
      }
    }
  }
}

__launch_bounds__(256, 1)
__global__ void fused_persist(const unsigned short* __restrict__ Wg0h, const unsigned short* __restrict__ Wc0h,
                              const unsigned short* __restrict__ Wg1, const unsigned short* __restrict__ Wc1,
                              const float* __restrict__ Xg0p, const float* __restrict__ Xc0p,
                              const float* __restrict__ bg1p, const float* __restrict__ bc1,
                              const float* __restrict__ hidden,
                              unsigned short* __restrict__ H0ALL, unsigned short* __restrict__ H1ALL,
                              const unsigned short* __restrict__ H0INITB, const unsigned short* __restrict__ H1INITB,
                              unsigned short* __restrict__ RH0, unsigned short* __restrict__ RH1,
                              int* __restrict__ stamps, float* __restrict__ hidden_out,
                              const unsigned short* __restrict__ Wout_f, const float* __restrict__ bout,
                              float* __restrict__ out) {
  extern __shared__ __align__(16) char smem[];
  int wg = blockIdx.x;
  if (wg >= NREC) {
    worker_path(wg - NREC, H1ALL, Wout_f, bout, out, stamps, smem);
    return;
  }
  int g = wg & 31;
  if (wg < 32)
    rec_layer<16, 0>(g, Wg0h, Wc0h, Xg0p, Xc0p, bg1p, bc1, hidden, H0ALL, H1ALL,
                     H0INITB, H1INITB, RH0, RH1, stamps, hidden_out, smem);
  else
    rec_layer<32, 1>(g, Wg1, Wc1, Xg0p, Xc0p, bg1p, bc1, hidden, H0ALL, H1ALL,
                     H0INITB, H1INITB, RH0, RH1, stamps, hidden_out, smem);
}

static inline int gridFor(long long n) { return (int)((n + 255) / 256); }

extern "C" void kernel_launch(void* const* d_in, const int* in_sizes, int n_in,
                              void* d_out, int out_size, void* d_ws, size_t ws_size,
                              hipStream_t stream) {
  const int*   inputs = (const int*)d_in[0];
  const float* hidden = (const float*)d_in[1];
  const float* embtab = (const float*)d_in[2];
  const float* Wg0 = (const float*)d_in[3];
  const float* bg0 = (const float*)d_in[4];
  const float* Wc0 = (const float*)d_in[5];
  const float* bc0 = (const float*)d_in[6];
  const float* Wg1 = (const float*)d_in[7];
  const float* bg1 = (const float*)d_in[8];
  const float* Wc1 = (const float*)d_in[9];
  const float* bc1 = (const float*)d_in[10];
  const float* Wout = (const float*)d_in[11];
  const float* bout = (const float*)d_in[12];
  float* out = (float*)d_out;

  // ---- workspace carve ----
  char* p = (char*)d_ws;
  size_t off = 0;
  auto carve = [&](size_t bytes) { char* r = p + off; off += (bytes + 255) & ~(size_t)255; return (void*)r; };
  unsigned short* XA     = (unsigned short*)carve((size_t)8192 * 512 * 2);
  unsigned short* Wg0x_f = (unsigned short*)carve((size_t)512 * 1024 * 2);
  unsigned short* Wg0h_f = (unsigned short*)carve((size_t)512 * 1024 * 2);
  unsigned short* Wc0x_f = (unsigned short*)carve((size_t)512 * 512 * 2);
  unsigned short* Wc0h_f = (unsigned short*)carve((size_t)512 * 512 * 2);
  unsigned short* Wg1_f  = (unsigned short*)carve((size_t)1024 * 1024 * 2);
  unsigned short* Wc1_f  = (unsigned short*)carve((size_t)1024 * 512 * 2);
  unsigned short* Wout_f = (unsigned short*)carve((size_t)512 * 10240 * 2);
  float* Xg0p = (float*)carve((size_t)8192 * 1024 * 4);
  float* Xc0p = (float*)carve((size_t)8192 * 512 * 4);
  unsigned short* H1ALL  = (unsigned short*)carve((size_t)128 * 32768 * 2);
  unsigned short* H0ALL  = (unsigned short*)carve((size_t)128 * 32768 * 2);
  unsigned short* H0INITB= (unsigned short*)carve((size_t)32768 * 2);
  unsigned short* H1INITB= (unsigned short*)carve((size_t)32768 * 2);
  unsigned short* RH0 = (unsigned short*)carve((size_t)32768 * 2);
  unsigned short* RH1 = (unsigned short*)carve((size_t)32768 * 2);
  float* bg0p = (float*)carve(1024 * 4);
  float* bg1p = (float*)carve(1024 * 4);
  int* stamps = (int*)carve(3072 * 4);
  if (off > ws_size) return;

  // ---- pack weights into fragment-linear bf16 ----
  pack_frag<<<gridFor(64LL * 16 * 64), 256, 0, stream>>>(Wg0, Wg0x_f, 16, 0,   1024, 64, 1, 1024);
  pack_frag<<<gridFor(64LL * 16 * 64), 256, 0, stream>>>(Wg0, Wg0h_f, 16, 512, 1024, 64, 1, 1024);
  pack_frag<<<gridFor(32LL * 16 * 64), 256, 0, stream>>>(Wc0, Wc0x_f, 16, 0,   512,  32, 0, 512);
  pack_frag<<<gridFor(32LL * 16 * 64), 256, 0, stream>>>(Wc0, Wc0h_f, 16, 512, 512,  32, 0, 512);
  pack_frag<<<gridFor(64LL * 32 * 64), 256, 0, stream>>>(Wg1, Wg1_f,  32, 0,   1024, 64, 1, 1024);
  pack_frag<<<gridFor(32LL * 32 * 64), 256, 0, stream>>>(Wc1, Wc1_f,  32, 0,   512,  32, 0, 512);
  pack_frag<<<gridFor(640LL * 16 * 64), 256, 0, stream>>>(Wout, Wout_f, 16, 0, 10000, 640, 0, 10000);
  pack_bias<<<4, 256, 0, stream>>>(bg0, bg1, bg0p, bg1p);

  // ---- embedding + state/stamp init ----
  embed_gather<<<gridFor((long long)SEQ * 64 * 64), 256, 0, stream>>>(inputs, embtab, XA);
  init_states<<<gridFor(32768), 256, 0, stream>>>(hidden, H0INITB, H1INITB, stamps);

  // ---- precompute x-parts of layer-0 gates/cell ----
  gemm128<<<dim3(8, 64), 256, 0, stream>>>(XA, Wg0x_f, bg0p, Xg0p, 1024, 1024);
  gemm128<<<dim3(4, 64), 256, 0, stream>>>(XA, Wc0x_f, bc0, Xc0p, 512, 512);

  // ---- fused persistent: 64 rec WGs (per-wave pipelines) + 192 workers ----
  // 98304B dynamic LDS (L1 weights) -> 1 WG/CU everywhere.
  fused_persist<<<NTOT, 256, 98304, stream>>>(Wg0h_f, Wc0h_f, Wg1_f, Wc1_f, Xg0p, Xc0p,
                                              bg1p, bc1, hidden, H0ALL, H1ALL,
                                              H0INITB, H1INITB, RH0, RH1,
                                              stamps, out + (size_t)81920000,
                                              Wout_f, bout, out);
}

// Round 12
// 1286.902 us; speedup vs baseline: 1.0872x; 1.0872x over previous
//
#include <hip/hip_runtime.h>
#include <cstdint>
#include <cstddef>

#define SEQ 128
#define BATCH 64
#define NVOCAB 10000
#define NREC 32
#define NWORK 224
#define NTOT 256

typedef __attribute__((ext_vector_type(8))) short short8;
typedef __attribute__((ext_vector_type(4))) float f32x4;

__device__ __forceinline__ unsigned short f2b(float f) {
  union { float f; unsigned u; } c; c.f = f;
  unsigned u = c.u;
  unsigned r = (u + 0x7fffu + ((u >> 16) & 1u)) >> 16;
  return (unsigned short)r;
}

__device__ __forceinline__ f32x4 mfma16(short8 a, short8 b, f32x4 c) {
  return __builtin_amdgcn_mfma_f32_16x16x32_bf16(a, b, c, 0, 0, 0);
}

// Coherent (cross-XCD) ops: bypass L1+L2, served at the coherence point.
__device__ __forceinline__ short8 ldg_coh(const unsigned short* p) {
  short8 r;
  asm volatile("global_load_dwordx4 %0, %1, off sc0 sc1" : "=v"(r) : "v"(p));
  return r;
}
__device__ __forceinline__ void stg_coh(unsigned short* p, short8 v) {
  asm volatile("global_store_dwordx4 %0, %1, off sc0 sc1" :: "v"(p), "v"(v) : "memory");
}
__device__ __forceinline__ void st_stamp(int* p, int v) {
  asm volatile("global_store_dword %0, %1, off sc0 sc1" :: "v"(p), "v"(v) : "memory");
}
__device__ __forceinline__ int ld_stamp(const int* p) {
  int r;
  asm volatile("global_load_dword %0, %1, off sc0 sc1" : "=v"(r) : "v"(p));
  return r;
}

// Wait until the first 16 words of one stamp line are >= need. Per-wave.
template<int SLP>
__device__ __forceinline__ void wait16(const int* line, int need) {
  if (need < 0) return;
  int idx = threadIdx.x & 15;
  int guard = 0;
  for (;;) {
    int v = ld_stamp(line + idx);
    asm volatile("s_waitcnt vmcnt(0)" ::: "memory");
    if (__all(v >= need)) return;
    __builtin_amdgcn_s_sleep(SLP);
    if (++guard > 3000000) return;  // bail to wrong-output, never hang
  }
}

// ---------------- packing: src f32 (K x N row-major) -> frag-linear bf16 ----
__global__ void pack_frag(const float* __restrict__ src, unsigned short* __restrict__ dst,
                          int ksteps, int row_off, int src_ld, int ntiles, int nreal) {
  int tid = blockIdx.x * 256 + threadIdx.x;
  int total = ntiles * ksteps * 64;
  if (tid >= total) return;
  int l = tid & 63;
  int ks = (tid >> 6) % ksteps;
  int nt = tid / (64 * ksteps);
  int n = nt * 16 + (l & 15);
  bool valid = (n < nreal);
  int k0 = row_off + ks * 32 + ((l >> 4) << 3);
  short8 o;
  for (int j = 0; j < 8; ++j) {
    float x = valid ? src[(size_t)(k0 + j) * src_ld + n] : 0.f;
    o[j] = (short)f2b(x);
  }
  *reinterpret_cast<short8*>(&dst[(size_t)tid * 8]) = o;
}

// ------------- embedding gather into kmat layout [t][ktile][row][8] bf16 ----
__global__ void embed_gather(const int* __restrict__ inp, const float* __restrict__ tab,
                             unsigned short* __restrict__ XA) {
  int tid = blockIdx.x * 256 + threadIdx.x;
  if (tid >= SEQ * 64 * 64) return;
  int row = tid & 63;
  int kt = (tid >> 6) & 63;
  int t = tid >> 12;
  int v = inp[t * BATCH + row];
  const float* s = &tab[(size_t)v * 512 + kt * 8];
  const float scale = 22.627416997969522f; // sqrt(512)
  short8 o;
  for (int j = 0; j < 8; ++j) o[j] = (short)f2b(s[j] * scale);
  *reinterpret_cast<short8*>(&XA[(size_t)tid * 8]) = o;
}

// ------------- init: h0/h1 initial bf16 kmat buffers, stamps=-1 ----
__global__ void init_states(const float* __restrict__ hid, unsigned short* __restrict__ H0INITB,
                            unsigned short* __restrict__ H1INITB, int* __restrict__ stamps) {
  int idx = blockIdx.x * 256 + threadIdx.x;
  if (idx < 24 * 64) stamps[idx] = -1;
  if (idx >= 64 * 512) return;
  int row = idx >> 9, c = idx & 511;
  size_t ko = (((size_t)(c >> 3)) * 64 + row) * 8 + (c & 7);
  H0INITB[ko] = f2b(hid[idx]);
  H1INITB[ko] = f2b(hid[64 * 512 + idx]);
}

// ------------- generic 128x128 LDS-tiled bf16 GEMM, K=512 (prologue only) ----
__launch_bounds__(256, 2)
__global__ void gemm128(const unsigned short* __restrict__ A, const unsigned short* __restrict__ Bf,
                        const float* __restrict__ bias, float* __restrict__ C,
                        int Nld, int Nreal) {
  __shared__ __align__(16) unsigned short ldsA[16 * 512];
  __shared__ __align__(16) unsigned short ldsB[16 * 512];
  int nb = blockIdx.x, yb = blockIdx.y;
  int l = threadIdx.x & 63, w = threadIdx.x >> 6;
  int mh = w >> 1, nh = w & 1;
  f32x4 acc[4][4] = {};
  for (int ko = 0; ko < 8; ++ko) {
    __syncthreads();
    for (int j = 0; j < 4; ++j) {
      int c = w * 4 + j;
      int m8 = c >> 1, ks = c & 1;
      int t = yb * 2 + (m8 >> 2);
      int kt = ko * 8 + ks * 4 + (l >> 4);
      int row = (m8 & 3) * 16 + (l & 15);
      size_t gidx = (((size_t)t * 64 + kt) * 64 + row) * 8;
      *reinterpret_cast<short8*>(&ldsA[(size_t)c * 512 + l * 8]) =
          *reinterpret_cast<const short8*>(&A[gidx]);
      size_t gb = (((size_t)(nb * 8 + (c >> 1)) * 16) + (size_t)(ko * 2 + (c & 1))) * 512 + (size_t)l * 8;
      *reinterpret_cast<short8*>(&ldsB[(size_t)c * 512 + l * 8]) =
          *reinterpret_cast<const short8*>(&Bf[gb]);
    }
    __syncthreads();
    for (int ks = 0; ks < 2; ++ks) {
      short8 a[4], b[4];
      for (int mt = 0; mt < 4; ++mt) {
        int m8 = mh * 4 + mt;
        a[mt] = *reinterpret_cast<const short8*>(&ldsA[((size_t)(m8 * 2 + ks) * 64 + l) * 8]);
      }
      for (int nt = 0; nt < 4; ++nt) {
        int n8 = nh * 4 + nt;
        b[nt] = *reinterpret_cast<const short8*>(&ldsB[((size_t)(n8 * 2 + ks) * 64 + l) * 8]);
      }
      for (int mt = 0; mt < 4; ++mt)
        for (int nt = 0; nt < 4; ++nt)
          acc[mt][nt] = mfma16(a[mt], b[nt], acc[mt][nt]);
    }
  }
  for (int mt = 0; mt < 4; ++mt) {
    for (int nt = 0; nt < 4; ++nt) {
      int col = nb * 128 + nh * 64 + nt * 16 + (l & 15);
      if (col >= Nreal) continue;
      float bv = bias[col];
      int row0 = yb * 128 + mh * 64 + mt * 16 + ((l >> 4) << 2);
      for (int r = 0; r < 4; ++r)
        C[(size_t)(row0 + r) * Nld + col] = acc[mt][nt][r] + bv;
    }
  }
}

// ------------- recurrence layer: 16 WGs x 32 cols, K-split waves ----
// Stamp rows (64 ints, words 0..15 used): 0-3 SR0, 4-7 SR1, 8-11 SH0,
// 12-15 SH1, 16-23 SHW. Gate cols per WG: u = [32g,32g+32), r = same + 512.
// Weight packs are mode-0 (plain): u-tiles nt=2g,2g+1; r-tiles nt=32+2g,+1.
template<int KSTEPS, int LAYER>
__device__ void rec_layer(
    int g, const unsigned short* __restrict__ Wg, const unsigned short* __restrict__ Wc,
    const float* __restrict__ Xg0p, const float* __restrict__ Xc0p,
    const float* __restrict__ bg1, const float* __restrict__ bc1,
    const float* __restrict__ hidden,
    unsigned short* __restrict__ H0ALL, unsigned short* __restrict__ H1ALL,
    const unsigned short* __restrict__ H0INITB, const unsigned short* __restrict__ H1INITB,
    unsigned short* __restrict__ RH0, unsigned short* __restrict__ RH1,
    int* __restrict__ stamps, float* __restrict__ hidden_out, char* smem) {
  constexpr int KQ = KSTEPS / 4;
  const int tid = threadIdx.x;
  const int l = tid & 63, w = tid >> 6;
  const int s = l & 15, q = l >> 4;
  const int erow = tid & 63, ekg = tid >> 6;   // epilogue mapping: 8 cols each

  unsigned short* WcL = (unsigned short*)smem;                       // L1 cell tiles (64KB)
  float (*red)[64][65] = (float(*)[64][65])(smem + 65536);           // 66560B
  float (*u_lds)[33] = (float(*)[33])(smem + 65536 + 66560);         // 8448B
  float (*hf)[33] = (float(*)[33])(smem + 65536 + 66560 + 8448);     // 8448B

  int* SR   = stamps + (LAYER ? 4 : 0) * 64;
  int* SH0  = stamps + 8 * 64;
  int* SH1  = stamps + 12 * 64;
  int* SHW  = stamps + 16 * 64;
  int* mySH = LAYER ? SH1 : SH0;
  const int repw = ((g + w) & 3) * 64;
  unsigned short* myRH = LAYER ? RH1 : RH0;

  // ---- gate weight frags -> VGPR (mode-0 pack; K-split by wave) ----
  short8 bg[2][2][KQ];   // [u/r][nt_local][kk]
#pragma unroll
  for (int nl = 0; nl < 2; ++nl)
#pragma unroll
    for (int kk = 0; kk < KQ; ++kk) {
      int ks = w * KQ + kk;
      bg[0][nl][kk] = *reinterpret_cast<const short8*>(
          &Wg[(((size_t)(2 * g + nl) * KSTEPS + ks) * 64 + l) * 8]);
      bg[1][nl][kk] = *reinterpret_cast<const short8*>(
          &Wg[(((size_t)(32 + 2 * g + nl) * KSTEPS + ks) * 64 + l) * 8]);
    }
  // ---- cell weights: L0 -> VGPR; L1 -> LDS (64KB) ----
  short8 bc[2][KQ];
  if constexpr (LAYER == 0) {
#pragma unroll
    for (int nl = 0; nl < 2; ++nl)
#pragma unroll
      for (int kk = 0; kk < KQ; ++kk) {
        int ks = w * KQ + kk;
        bc[nl][kk] = *reinterpret_cast<const short8*>(
            &Wc[(((size_t)(2 * g + nl) * KSTEPS + ks) * 64 + l) * 8]);
      }
  } else {
    const short8* src = reinterpret_cast<const short8*>(Wc + (size_t)(2 * g) * KSTEPS * 512);
    short8* dst = reinterpret_cast<short8*>(WcL);
    for (int i = tid; i < 2 * KSTEPS * 64; i += 256) dst[i] = src[i];
  }

  // ---- f32 h master slice + per-thread biases ----
  {
#pragma unroll
    for (int j = 0; j < 8; ++j)
      hf[erow][ekg * 8 + j] = hidden[(size_t)LAYER * 32768 + (size_t)erow * 512 + 32 * g + ekg * 8 + j];
  }
  float bu[8], br[8], bcv[8];
  if constexpr (LAYER) {
#pragma unroll
    for (int j = 0; j < 8; ++j) {
      bu[j]  = bg1[32 * g + ekg * 8 + j];
      br[j]  = bg1[512 + 32 * g + ekg * 8 + j];
      bcv[j] = bc1[32 * g + ekg * 8 + j];
    }
  }
  __syncthreads();

  for (int t = 0; t < 128; ++t) {
    // ---- L0: prefetch X-part adds (no stamp dependency) ----
    float xu[8], xr[8], xc[8];
    if constexpr (LAYER == 0) {
      size_t rb = (size_t)(t * 64 + erow);
#pragma unroll
      for (int j = 0; j < 8; ++j) {
        xu[j] = Xg0p[rb * 1024 + 32 * g + ekg * 8 + j];
        xr[j] = Xg0p[rb * 1024 + 512 + 32 * g + ekg * 8 + j];
        xc[j] = Xc0p[rb * 512 + 32 * g + ekg * 8 + j];
      }
    }
    const unsigned short* A0 = LAYER ? (H0ALL + (size_t)t * 32768)
                                     : (t ? (H0ALL + (size_t)(t - 1) * 32768) : H0INITB);
    const unsigned short* A1 = nullptr;
    if (LAYER) A1 = t ? (H1ALL + (size_t)(t - 1) * 32768) : H1INITB;

    // ============ phase A: gates ============
    {
      f32x4 acc[4][4] = {};   // [mt][u0,u1,r0,r1]
      if constexpr (LAYER == 0) {
        wait16<1>(SH0 + repw, t - 1);
        short8 a[4][4];
#pragma unroll
        for (int kk = 0; kk < 4; ++kk) {
          int kl = w * 4 + kk;
#pragma unroll
          for (int mt = 0; mt < 4; ++mt)
            a[kk][mt] = ldg_coh(&A0[(((size_t)(kl * 4 + q)) * 64 + mt * 16 + s) * 8]);
        }
        asm volatile("s_waitcnt vmcnt(0)" ::: "memory");
        __builtin_amdgcn_sched_barrier(0);
#pragma unroll
        for (int kk = 0; kk < 4; ++kk)
#pragma unroll
          for (int mt = 0; mt < 4; ++mt) {
            acc[mt][0] = mfma16(a[kk][mt], bg[0][0][kk], acc[mt][0]);
            acc[mt][1] = mfma16(a[kk][mt], bg[0][1][kk], acc[mt][1]);
            acc[mt][2] = mfma16(a[kk][mt], bg[1][0][kk], acc[mt][2]);
            acc[mt][3] = mfma16(a[kk][mt], bg[1][1][kk], acc[mt][3]);
          }
      } else {
        // per-wave dependency wait: w0,w1 = h0-part, w2,w3 = h1-part
        if (w >= 2) wait16<1>(SH1 + repw, t - 1);
        else        wait16<1>(SH0 + repw, t);
        const unsigned short* ab = (w >= 2) ? A1 : A0;
#pragma unroll
        for (int hb = 0; hb < 2; ++hb) {
          short8 a[4][4];
#pragma unroll
          for (int kk2 = 0; kk2 < 4; ++kk2) {
            int kl = (w & 1) * 8 + hb * 4 + kk2;
#pragma unroll
            for (int mt = 0; mt < 4; ++mt)
              a[kk2][mt] = ldg_coh(&ab[(((size_t)(kl * 4 + q)) * 64 + mt * 16 + s) * 8]);
          }
          asm volatile("s_waitcnt vmcnt(0)" ::: "memory");
          __builtin_amdgcn_sched_barrier(0);
#pragma unroll
          for (int kk2 = 0; kk2 < 4; ++kk2) {
            int kkg = hb * 4 + kk2;
#pragma unroll
            for (int mt = 0; mt < 4; ++mt) {
              acc[mt][0] = mfma16(a[kk2][mt], bg[0][0][kkg], acc[mt][0]);
              acc[mt][1] = mfma16(a[kk2][mt], bg[0][1][kkg], acc[mt][1]);
              acc[mt][2] = mfma16(a[kk2][mt], bg[1][0][kkg], acc[mt][2]);
              acc[mt][3] = mfma16(a[kk2][mt], bg[1][1][kkg], acc[mt][3]);
            }
          }
        }
      }
#pragma unroll
      for (int mt = 0; mt < 4; ++mt)
#pragma unroll
        for (int nc = 0; nc < 4; ++nc)
#pragma unroll
          for (int r = 0; r < 4; ++r)
            red[w][mt * 16 + q * 4 + r][nc * 16 + s] = acc[mt][nc][r];
    }
    __syncthreads();
    {  // epilogue A: every thread does 8 u (-> LDS) + 8 r (-> 16B coherent store)
      short8 o;
#pragma unroll
      for (int j = 0; j < 8; ++j) {
        int cu = ekg * 8 + j, cr = 32 + ekg * 8 + j;
        float su = red[0][erow][cu] + red[1][erow][cu] + red[2][erow][cu] + red[3][erow][cu];
        float sr = red[0][erow][cr] + red[1][erow][cr] + red[2][erow][cr] + red[3][erow][cr];
        su += LAYER ? bu[j] : xu[j];
        sr += LAYER ? br[j] : xr[j];
        u_lds[erow][cu] = 1.f / (1.f + __expf(-su));
        float gate = 1.f / (1.f + __expf(-sr));
        o[j] = (short)f2b(gate * hf[erow][cu]);
      }
      stg_coh(&myRH[((size_t)(4 * g + ekg) * 64 + erow) * 8], o);
    }
    asm volatile("s_waitcnt vmcnt(0)" ::: "memory");
    __syncthreads();
    if (tid == 0) {
#pragma unroll
      for (int r4 = 0; r4 < 4; ++r4) st_stamp(&SR[r4 * 64 + g], t);
    }

    // ============ phase B: cell + state update ============
    {
      f32x4 acc[4][2] = {};   // [mt][nt]
      if constexpr (LAYER == 0) {
        wait16<1>(SR + repw, t);
        short8 a[4][4];
#pragma unroll
        for (int kk = 0; kk < 4; ++kk) {
          int kl = w * 4 + kk;
#pragma unroll
          for (int mt = 0; mt < 4; ++mt)
            a[kk][mt] = ldg_coh(&RH0[(((size_t)(kl * 4 + q)) * 64 + mt * 16 + s) * 8]);
        }
        asm volatile("s_waitcnt vmcnt(0)" ::: "memory");
        __builtin_amdgcn_sched_barrier(0);
#pragma unroll
        for (int kk = 0; kk < 4; ++kk)
#pragma unroll
          for (int mt = 0; mt < 4; ++mt) {
            acc[mt][0] = mfma16(a[kk][mt], bc[0][kk], acc[mt][0]);
            acc[mt][1] = mfma16(a[kk][mt], bc[1][kk], acc[mt][1]);
          }
      } else {
        // w0,1: h0-part (gated by phase A's SH0 wait); w2,3: rh1-part
        if (w >= 2) wait16<1>(SR + repw, t);
        const unsigned short* ab = (w >= 2) ? myRH : A0;
#pragma unroll
        for (int hb = 0; hb < 2; ++hb) {
          short8 a[4][4];
#pragma unroll
          for (int kk2 = 0; kk2 < 4; ++kk2) {
            int kl = (w & 1) * 8 + hb * 4 + kk2;
#pragma unroll
            for (int mt = 0; mt < 4; ++mt)
              a[kk2][mt] = ldg_coh(&ab[(((size_t)(kl * 4 + q)) * 64 + mt * 16 + s) * 8]);
          }
          asm volatile("s_waitcnt vmcnt(0)" ::: "memory");
          __builtin_amdgcn_sched_barrier(0);
#pragma unroll
          for (int kk2 = 0; kk2 < 4; ++kk2) {
            int ks = w * 8 + hb * 4 + kk2;
#pragma unroll
            for (int mt = 0; mt < 4; ++mt) {
              short8 b0 = *reinterpret_cast<const short8*>(&WcL[(((size_t)(0 * KSTEPS + ks)) * 64 + l) * 8]);
              short8 b1 = *reinterpret_cast<const short8*>(&WcL[(((size_t)(1 * KSTEPS + ks)) * 64 + l) * 8]);
              acc[mt][0] = mfma16(a[kk2][mt], b0, acc[mt][0]);
              acc[mt][1] = mfma16(a[kk2][mt], b1, acc[mt][1]);
            }
          }
        }
      }
#pragma unroll
      for (int mt = 0; mt < 4; ++mt)
#pragma unroll
        for (int nt = 0; nt < 2; ++nt)
#pragma unroll
          for (int r = 0; r < 4; ++r)
            red[w][mt * 16 + q * 4 + r][nt * 16 + s] = acc[mt][nt][r];
    }
    __syncthreads();
    {  // epilogue B: 8 h-values per thread, 16B coherent store to ring
      short8 o;
#pragma unroll
      for (int j = 0; j < 8; ++j) {
        int c = ekg * 8 + j;
        float sum = red[0][erow][c] + red[1][erow][c] + red[2][erow][c] + red[3][erow][c];
        sum += LAYER ? bcv[j] : xc[j];
        float cv = tanhf(sum);
        float hp = hf[erow][c];
        float hn = hp + u_lds[erow][c] * (cv - hp);
        hf[erow][c] = hn;
        o[j] = (short)f2b(hn);
      }
      unsigned short* Hdst = (LAYER ? H1ALL : H0ALL) + (size_t)t * 32768;
      stg_coh(&Hdst[((size_t)(4 * g + ekg) * 64 + erow) * 8], o);
    }
    asm volatile("s_waitcnt vmcnt(0)" ::: "memory");
    __syncthreads();
    if (tid == 0) {
#pragma unroll
      for (int r4 = 0; r4 < 4; ++r4) st_stamp(&mySH[r4 * 64 + g], t);
      if (LAYER) {
#pragma unroll
        for (int r8 = 0; r8 < 8; ++r8) st_stamp(&SHW[r8 * 64 + g], t);
      }
    }
  }

  // ---- final hidden (f32); hf stable after the last pre-stamp __syncthreads ----
#pragma unroll
  for (int j = 0; j < 8; ++j)
    hidden_out[(size_t)LAYER * 32768 + (size_t)erow * 512 + 32 * g + ekg * 8 + j] = hf[erow][ekg * 8 + j];
}

// ------------- worker path: logits tiles, nb-major (L2-resident B-block) ----
__device__ void worker_path(int wid, const unsigned short* __restrict__ A,
                            const unsigned short* __restrict__ Bf,
                            const float* __restrict__ bias, float* __restrict__ C,
                            const int* __restrict__ stamps, char* smem) {
  unsigned short* ldsA = (unsigned short*)smem;
  unsigned short* ldsB = (unsigned short*)(smem + 16384);
  const int* rep = stamps + (16 + (wid & 7)) * 64;
  int l = threadIdx.x & 63, w = threadIdx.x >> 6;
  int mh = w >> 1, nh = w & 1;
  int nb = wid % 80;
  int helper = wid / 80;                  // 0,1 for all nb; 2 exists for nb<64
  int nhelp = (nb < 64) ? 3 : 2;
  for (int tp = helper; tp < 64; tp += nhelp) {
    wait16<16>(rep, 2 * tp + 1);
    f32x4 acc[4][4] = {};
    for (int ko = 0; ko < 8; ++ko) {
      __syncthreads();
      for (int j = 0; j < 4; ++j) {
        int c = w * 4 + j;
        int m8 = c >> 1, ks = c & 1;
        int t = tp * 2 + (m8 >> 2);
        int kt = ko * 8 + ks * 4 + (l >> 4);
        int row = (m8 & 3) * 16 + (l & 15);
        size_t gidx = (((size_t)t * 64 + kt) * 64 + row) * 8;
        *reinterpret_cast<short8*>(&ldsA[(size_t)c * 512 + l * 8]) =
            *reinterpret_cast<const short8*>(&A[gidx]);
        size_t gb = (((size_t)(nb * 8 + (c >> 1)) * 16) + (size_t)(ko * 2 + (c & 1))) * 512 + (size_t)l * 8;
        *reinterpret_cast<short8*>(&ldsB[(size_t)c * 512 + l * 8]) =
            *reinterpret_cast<const short8*>(&Bf[gb]);
      }
      __syncthreads();
      for (int ks = 0; ks < 2; ++ks) {
        short8 a[4], b[4];
        for (int mt = 0; mt < 4; ++mt)
          a[mt] = *reinterpret_cast<const short8*>(&ldsA[((size_t)((mh * 4 + mt) * 2 + ks) * 64 + l) * 8]);
        for (int nt = 0; nt < 4; ++nt)
          b[nt] = *reinterpret_cast<const short8*>(&ldsB[((size_t)((nh * 4 + nt) * 2 + ks) * 64 + l) * 8]);
        for (int mt = 0; mt < 4; ++mt)
          for (int nt = 0; nt < 4; ++nt)
            acc[mt][nt] = mfma16(a[mt], b[nt], acc[mt][nt]);
      }
    }
    for (int mt = 0; mt < 4; ++mt) {
      for (int nt = 0; nt < 4; ++nt) {
        int col = nb * 128 + nh * 64 + nt * 16 + (l & 15);
        if (col >= NVOCAB) continue;
        float bv = bias[col];
        int row0 = tp * 128 + mh * 64 + mt * 16 + ((l >> 4) << 2);
        for (int r = 0; r < 4; ++r)
          C[(size_t)(row0 + r) * NVOCAB + col] = acc[mt][nt][r] + bv;
      }
    }
  }
}

__launch_bounds__(256, 1)
__global__ void fused_persist(const unsigned short* __restrict__ Wg0h, const unsigned short* __restrict__ Wc0h,
                              const unsigned short* __restrict__ Wg1, const unsigned short* __restrict__ Wc1,
                              const float* __restrict__ Xg0p, const float* __restrict__ Xc0p,
                              const float* __restrict__ bg1, const float* __restrict__ bc1,
                              const float* __restrict__ hidden,
                              unsigned short* __restrict__ H0ALL, unsigned short* __restrict__ H1ALL,
                              const unsigned short* __restrict__ H0INITB, const unsigned short* __restrict__ H1INITB,
                              unsigned short* __restrict__ RH0, unsigned short* __restrict__ RH1,
                              int* __restrict__ stamps, float* __restrict__ hidden_out,
                              const unsigned short* __restrict__ Wout_f, const float* __restrict__ bout,
                              float* __restrict__ out) {
  extern __shared__ __align__(16) char smem[];
  int wg = blockIdx.x;
  if (wg >= NREC) {
    worker_path(wg - NREC, H1ALL, Wout_f, bout, out, stamps, smem);
    return;
  }
  if (wg < 16)
    rec_layer<16, 0>(wg, Wg0h, Wc0h, Xg0p, Xc0p, bg1, bc1, hidden, H0ALL, H1ALL,
                     H0INITB, H1INITB, RH0, RH1, stamps, hidden_out, smem);
  else
    rec_layer<32, 1>(wg - 16, Wg1, Wc1, Xg0p, Xc0p, bg1, bc1, hidden, H0ALL, H1ALL,
                     H0INITB, H1INITB, RH0, RH1, stamps, hidden_out, smem);
}

static inline int gridFor(long long n) { return (int)((n + 255) / 256); }

extern "C" void kernel_launch(void* const* d_in, const int* in_sizes, int n_in,
                              void* d_out, int out_size, void* d_ws, size_t ws_size,
                              hipStream_t stream) {
  const int*   inputs = (const int*)d_in[0];
  const float* hidden = (const float*)d_in[1];
  const float* embtab = (const float*)d_in[2];
  const float* Wg0 = (const float*)d_in[3];
  const float* bg0 = (const float*)d_in[4];
  const float* Wc0 = (const float*)d_in[5];
  const float* bc0 = (const float*)d_in[6];
  const float* Wg1 = (const float*)d_in[7];
  const float* bg1 = (const float*)d_in[8];
  const float* Wc1 = (const float*)d_in[9];
  const float* bc1 = (const float*)d_in[10];
  const float* Wout = (const float*)d_in[11];
  const float* bout = (const float*)d_in[12];
  float* out = (float*)d_out;

  // ---- workspace carve ----
  char* p = (char*)d_ws;
  size_t off = 0;
  auto carve = [&](size_t bytes) { char* r = p + off; off += (bytes + 255) & ~(size_t)255; return (void*)r; };
  unsigned short* XA     = (unsigned short*)carve((size_t)8192 * 512 * 2);
  unsigned short* Wg0x_f = (unsigned short*)carve((size_t)512 * 1024 * 2);
  unsigned short* Wg0h_f = (unsigned short*)carve((size_t)512 * 1024 * 2);
  unsigned short* Wc0x_f = (unsigned short*)carve((size_t)512 * 512 * 2);
  unsigned short* Wc0h_f = (unsigned short*)carve((size_t)512 * 512 * 2);
  unsigned short* Wg1_f  = (unsigned short*)carve((size_t)1024 * 1024 * 2);
  unsigned short* Wc1_f  = (unsigned short*)carve((size_t)1024 * 512 * 2);
  unsigned short* Wout_f = (unsigned short*)carve((size_t)512 * 10240 * 2);
  float* Xg0p = (float*)carve((size_t)8192 * 1024 * 4);
  float* Xc0p = (float*)carve((size_t)8192 * 512 * 4);
  unsigned short* H1ALL  = (unsigned short*)carve((size_t)128 * 32768 * 2);
  unsigned short* H0ALL  = (unsigned short*)carve((size_t)128 * 32768 * 2);
  unsigned short* H0INITB= (unsigned short*)carve((size_t)32768 * 2);
  unsigned short* H1INITB= (unsigned short*)carve((size_t)32768 * 2);
  unsigned short* RH0 = (unsigned short*)carve((size_t)32768 * 2);
  unsigned short* RH1 = (unsigned short*)carve((size_t)32768 * 2);
  int* stamps = (int*)carve(24 * 64 * 4);
  if (off > ws_size) return;

  // ---- pack weights into frag-linear bf16 (all mode-0 / plain col order) ----
  pack_frag<<<gridFor(64LL * 16 * 64), 256, 0, stream>>>(Wg0, Wg0x_f, 16, 0,   1024, 64, 1024);
  pack_frag<<<gridFor(64LL * 16 * 64), 256, 0, stream>>>(Wg0, Wg0h_f, 16, 512, 1024, 64, 1024);
  pack_frag<<<gridFor(32LL * 16 * 64), 256, 0, stream>>>(Wc0, Wc0x_f, 16, 0,   512,  32, 512);
  pack_frag<<<gridFor(32LL * 16 * 64), 256, 0, stream>>>(Wc0, Wc0h_f, 16, 512, 512,  32, 512);
  pack_frag<<<gridFor(64LL * 32 * 64), 256, 0, stream>>>(Wg1, Wg1_f,  32, 0,   1024, 64, 1024);
  pack_frag<<<gridFor(32LL * 32 * 64), 256, 0, stream>>>(Wc1, Wc1_f,  32, 0,   512,  32, 512);
  pack_frag<<<gridFor(640LL * 16 * 64), 256, 0, stream>>>(Wout, Wout_f, 16, 0, 10000, 640, 10000);

  // ---- embedding + state/stamp init ----
  embed_gather<<<gridFor((long long)SEQ * 64 * 64), 256, 0, stream>>>(inputs, embtab, XA);
  init_states<<<gridFor(32768), 256, 0, stream>>>(hidden, H0INITB, H1INITB, stamps);

  // ---- precompute x-parts of layer-0 gates/cell (plain col order, direct bias) ----
  gemm128<<<dim3(8, 64), 256, 0, stream>>>(XA, Wg0x_f, bg0, Xg0p, 1024, 1024);
  gemm128<<<dim3(4, 64), 256, 0, stream>>>(XA, Wc0x_f, bc0, Xc0p, 512, 512);

  // ---- fused persistent: 32 fat rec WGs + 224 logits workers ----
  // dynamic LDS 148,992B -> 1 WG/CU.
  fused_persist<<<NTOT, 256, 148992, stream>>>(Wg0h_f, Wc0h_f, Wg1_f, Wc1_f, Xg0p, Xc0p,
                                               bg1, bc1, hidden, H0ALL, H1ALL,
                                               H0INITB, H1INITB, RH0, RH1,
                                               stamps, out + (size_t)81920000,
                                               Wout_f, bout, out);
}